// Round 11
// baseline (104.494 us; speedup 1.0000x reference)
//
#include <hip/hip_runtime.h>
#include <math.h>

// A3C batch-1 forward, R10: 20 blocks, halved producer sets, D folded into G.
//
// Model (R0-R9): bench = ~84.5us harness floor + kernel. Kernel terms:
// launch + post-poison-fill HBM drain (structure-insensitive) + hop chain
// where each hop costs ~straggler-max of its producer team. R9 proved the
// levers: halve producers / fold teams / fewer blocks => ~1us each.
// R10: B 16->8 blocks (32 h2 rows each), D folded into G (each G block
// computes its own 16 h4 rows, H4 exchange intra-team; own rows short-cut
// through LDS), NB 32->20.
//
// Teams (TPB=256), hops H2 -> H3 -> H4(intra-G) -> PT(intra-G):
//   B: blk 0..7   h1 redundant (W1 30KB first) + 32 h2 rows (W2 32KB) -> H2
//   C: blk 8..11  32 h3 rows (W3 32KB); recv H2 -> H3
//   G: blk 12..19 16 h4 rows (W4 8KB) + 16 LSTM cells = 64 gate rows
//                 (W_hh 32KB early for g0, W_ih 32KB); recv H3 -> h4 ->
//                 exchange H4 -> gates -> LSTM(16) -> 7 head partials;
//                 G0 reduces 8x7 partials, softsign, writes out.

#define NB   20
#define TPB  256
#define MAGIC 0x3A3C5A17u

#define H2_OFF 0      // 256 pairs (16 lines)
#define H3_OFF 256    // 128 pairs (8 lines)
#define H4_OFF 384    // 128 pairs (8 lines)
#define PT_OFF 512    // 8 lines; G block g owns pairs [g*8 .. g*8+6]

__device__ __forceinline__ float lrelu(float v) { return v > 0.f ? v : 0.1f * v; }
__device__ __forceinline__ float sigm(float v)  { return 1.f / (1.f + __expf(-v)); }
__device__ __forceinline__ float dot4(float4 a, float4 b) {
    return a.x * b.x + a.y * b.y + a.z * b.z + a.w * b.w;
}

__device__ __forceinline__ void send(unsigned long long* p, float v) {
    unsigned lo = __float_as_uint(v);
    unsigned long long pk = (unsigned long long)lo |
                            ((unsigned long long)(lo ^ MAGIC) << 32);
    __hip_atomic_store(p, pk, __ATOMIC_RELAXED, __HIP_MEMORY_SCOPE_AGENT);
}
__device__ __forceinline__ float recv(unsigned long long* p) {
    unsigned long long pk =
        __hip_atomic_load(p, __ATOMIC_RELAXED, __HIP_MEMORY_SCOPE_AGENT);
    unsigned lo = (unsigned)pk, hi = (unsigned)(pk >> 32);
    if ((lo ^ MAGIC) == hi) return __uint_as_float(lo);
    __builtin_amdgcn_s_sleep(2);
    for (;;) {
        pk = __hip_atomic_load(p, __ATOMIC_RELAXED, __HIP_MEMORY_SCOPE_AGENT);
        lo = (unsigned)pk; hi = (unsigned)(pk >> 32);
        if ((lo ^ MAGIC) == hi) return __uint_as_float(lo);
        __builtin_amdgcn_s_sleep(8);
    }
}
__device__ __forceinline__ void touch(unsigned long long* p) {
    unsigned long long v =
        __hip_atomic_load(p, __ATOMIC_RELAXED, __HIP_MEMORY_SCOPE_AGENT);
    asm volatile("" :: "v"(v));
}

__global__ __launch_bounds__(TPB, 1) void a3c_fwd(
    const float* __restrict__ x, const float* __restrict__ hx, const float* __restrict__ cx,
    const float* __restrict__ w1, const float* __restrict__ b1,
    const float* __restrict__ w2, const float* __restrict__ b2,
    const float* __restrict__ w3, const float* __restrict__ b3,
    const float* __restrict__ w4, const float* __restrict__ b4,
    const float* __restrict__ w_ih, const float* __restrict__ b_ih,
    const float* __restrict__ w_hh, const float* __restrict__ b_hh,
    const float* __restrict__ w_critic, const float* __restrict__ b_critic,
    const float* __restrict__ w_actor, const float* __restrict__ b_actor,
    const float* __restrict__ w_actor2, const float* __restrict__ b_actor2,
    float* __restrict__ out, unsigned long long* __restrict__ wsp)
{
    const int blk = blockIdx.x, tid = threadIdx.x;

    if (blk < 8) {
        // ---- Team B: h1 (redundant, W1 first) + 32 h2 rows ----
        const int b = blk;
        if (tid < 4) touch(wsp + H2_OFF + b * 32 + tid * 8);  // send lines

        float a1[29];
        {
            const float* w1r = w1 + tid * 29;
            #pragma unroll
            for (int j = 0; j < 29; ++j) a1[j] = w1r[j];
        }
        const float bb1 = b1[tid];

        const int r2 = b * 32 + (tid >> 3), p2 = tid & 7;   // 32 floats/lane
        float4 a2[8];
        {
            const float4* wp = (const float4*)(w2 + r2 * 256 + p2 * 32);
            #pragma unroll
            for (int j = 0; j < 8; ++j) a2[j] = wp[j];
        }
        const float bb2 = b2[r2];

        __shared__ __align__(16) float x_s[32];
        __shared__ __align__(16) float h1_s[256];
        if (tid < 32) x_s[tid] = (tid < 29) ? x[tid] : 0.f;
        __syncthreads();

        {
            float s = 0.f;
            #pragma unroll
            for (int j = 0; j < 29; ++j) s += a1[j] * x_s[j];
            h1_s[tid] = lrelu(s + bb1);
        }
        __syncthreads();

        {
            const float4* hp = (const float4*)(h1_s + p2 * 32);
            float s = 0.f;
            #pragma unroll
            for (int j = 0; j < 8; ++j) s += dot4(a2[j], hp[j]);
            s += __shfl_xor(s, 1); s += __shfl_xor(s, 2); s += __shfl_xor(s, 4);
            if (p2 == 0) send(wsp + H2_OFF + r2, lrelu(s + bb2));
        }
        return;
    }

    if (blk < 12) {
        // ---- Team C: 32 h3 rows/blk ----
        const int c = blk - 8;
        if (tid < 16)       touch(wsp + H2_OFF + tid * 16);               // recv set
        else if (tid < 20)  touch(wsp + H3_OFF + c * 32 + (tid - 16) * 8); // send

        const int r3 = c * 32 + (tid >> 3), p3 = tid & 7;
        float4 a3[8];
        {
            const float4* wp = (const float4*)(w3 + r3 * 256 + p3 * 32);
            #pragma unroll
            for (int j = 0; j < 8; ++j) a3[j] = wp[j];
        }
        const float bb3 = b3[r3];

        __shared__ __align__(16) float h2_s[256];
        h2_s[tid] = recv(wsp + H2_OFF + tid);
        __syncthreads();

        const float4* hp = (const float4*)(h2_s + p3 * 32);
        float s = 0.f;
        #pragma unroll
        for (int j = 0; j < 8; ++j) s += dot4(a3[j], hp[j]);
        s += __shfl_xor(s, 1); s += __shfl_xor(s, 2); s += __shfl_xor(s, 4);
        if (p3 == 0) send(wsp + H3_OFF + r3, lrelu(s + bb3));
        return;
    }

    // ---- Team G: 16 h4 rows + 16 LSTM cells (64 gate rows) + epilogue ----
    {
        const int g = blk - 12;                       // [0,8)
        // prewarm: H3 recv set, own H4 send lines, PT line(s)
        if (tid < 8)                 touch(wsp + H3_OFF + tid * 16);
        else if (tid == 8)           touch(wsp + H4_OFF + g * 16);
        else if (tid == 9)           touch(wsp + H4_OFF + g * 16 + 8);
        else if (g > 0 && tid == 10) touch(wsp + PT_OFF + g * 8);
        else if (g == 0 && tid >= 10 && tid < 18)
                                     touch(wsp + PT_OFF + (tid - 10) * 8);

        const int r = tid >> 2, p = tid & 3;          // 64 gate rows x 4 x 32
        const int gate = r >> 4, cell = r & 15;
        const int grow = gate * 128 + g * 16 + cell;
        const int rl4 = tid >> 4, p4 = tid & 15;      // 16 h4 rows x 16 x 8

        // load order = need order: w_hh (g0 early), w4 (h4), w_ih (gates)
        float4 ah[8];
        {
            const float4* wp = (const float4*)(w_hh + grow * 128 + p * 32);
            #pragma unroll
            for (int j = 0; j < 8; ++j) ah[j] = wp[j];
        }
        float4 a4v0, a4v1;
        {
            const float4* wp = (const float4*)(w4 + (g * 16 + rl4) * 128 + p4 * 8);
            a4v0 = wp[0]; a4v1 = wp[1];
        }
        float4 ai[8];
        {
            const float4* wp = (const float4*)(w_ih + grow * 128 + p * 32);
            #pragma unroll
            for (int j = 0; j < 8; ++j) ai[j] = wp[j];
        }
        const float bsum = b_ih[grow] + b_hh[grow];
        const float bb4  = b4[g * 16 + rl4];

        __shared__ __align__(16) float hx_s[128];
        __shared__ __align__(16) float h3_s[128];
        __shared__ __align__(16) float h4_s[128];
        __shared__ __align__(16) float g_s[64];
        __shared__ __align__(16) float hn_s[16];
        __shared__ __align__(16) float hw_s[112];   // 7 heads x 16 cells
        __shared__ __align__(16) float hb_s[8];
        __shared__ __align__(16) float ps[64];      // G0: 7 heads x 8 blocks

        if (tid < 128) hx_s[tid] = hx[tid];
        float cxv = (tid < 16) ? cx[g * 16 + tid] : 0.f;
        if (tid < 112) {
            int o = tid >> 4, c = tid & 15;
            float v;
            if (o == 0)      v = w_critic[g * 16 + c];
            else if (o < 4)  v = w_actor [(o - 1) * 128 + g * 16 + c];
            else             v = w_actor2[(o - 4) * 128 + g * 16 + c];
            hw_s[tid] = v;
        }
        if (g == 0 && tid == 0) {
            hb_s[0] = b_critic[0];
            hb_s[1] = b_actor[0];  hb_s[2] = b_actor[1];  hb_s[3] = b_actor[2];
            hb_s[4] = b_actor2[0]; hb_s[5] = b_actor2[1]; hb_s[6] = b_actor2[2];
        }
        __syncthreads();

        // g0 = W_hh @ hx + biases (off critical path)
        float g0;
        {
            const float4* hp = (const float4*)(hx_s + p * 32);
            float s = 0.f;
            #pragma unroll
            for (int j = 0; j < 8; ++j) s += dot4(ah[j], hp[j]);
            s += __shfl_xor(s, 1); s += __shfl_xor(s, 2);
            g0 = s + bsum;
        }

        if (tid < 128) h3_s[tid] = recv(wsp + H3_OFF + tid);
        __syncthreads();

        { // own 16 h4 rows -> LDS + send
            const float4* hp = (const float4*)(h3_s + p4 * 8);
            float s = dot4(a4v0, hp[0]) + dot4(a4v1, hp[1]);
            s += __shfl_xor(s, 1); s += __shfl_xor(s, 2);
            s += __shfl_xor(s, 4); s += __shfl_xor(s, 8);
            if (p4 == 0) {
                float v = lrelu(s + bb4);
                h4_s[g * 16 + rl4] = v;
                send(wsp + H4_OFF + g * 16 + rl4, v);
            }
        }
        // fetch the other 112 h4 rows from L3
        if (tid < 128 && (tid >> 4) != g) h4_s[tid] = recv(wsp + H4_OFF + tid);
        __syncthreads();

        { // gates for 64 rows
            const float4* hp = (const float4*)(h4_s + p * 32);
            float s = 0.f;
            #pragma unroll
            for (int j = 0; j < 8; ++j) s += dot4(ai[j], hp[j]);
            s += __shfl_xor(s, 1); s += __shfl_xor(s, 2);
            if (p == 0) g_s[r] = g0 + s;   // r = gate*16 + cell
        }
        __syncthreads();

        if (tid < 16) {   // LSTM elementwise, 16 cells
            float ig = g_s[tid];
            float fg = g_s[16 + tid];
            float gg = g_s[32 + tid];
            float og = g_s[48 + tid];
            float c  = sigm(fg) * cxv + sigm(ig) * tanhf(gg);
            hn_s[tid] = sigm(og) * tanhf(c);
        }
        __syncthreads();

        if (tid < 7) {    // 7 head partials over this block's 16 cells
            const float* wc = hw_s + tid * 16;
            float s = 0.f;
            #pragma unroll
            for (int j = 0; j < 16; ++j) s += wc[j] * hn_s[j];
            if (g > 0) send(wsp + PT_OFF + g * 8 + tid, s);
            else       ps[tid * 8] = s + hb_s[tid];
        }

        if (g == 0) {
            if (tid < 56) {
                const int gg = (tid >> 3) + 1, h = tid & 7;
                if (h < 7) ps[h * 8 + gg] = recv(wsp + PT_OFF + gg * 8 + h);
            }
            __syncthreads();
            if (tid < 7) {
                const float* row = ps + tid * 8;
                float s = row[0] + row[1] + row[2] + row[3]
                        + row[4] + row[5] + row[6] + row[7];
                if (tid >= 1 && tid <= 3) s = s / (1.f + fabsf(s));
                out[tid] = s;
            }
        }
    }
}

extern "C" void kernel_launch(void* const* d_in, const int* in_sizes, int n_in,
                              void* d_out, int out_size, void* d_ws, size_t ws_size,
                              hipStream_t stream) {
    const float* x        = (const float*)d_in[0];
    const float* hx       = (const float*)d_in[1];
    const float* cx       = (const float*)d_in[2];
    const float* w1       = (const float*)d_in[3];
    const float* b1       = (const float*)d_in[4];
    const float* w2       = (const float*)d_in[5];
    const float* b2       = (const float*)d_in[6];
    const float* w3       = (const float*)d_in[7];
    const float* b3       = (const float*)d_in[8];
    const float* w4       = (const float*)d_in[9];
    const float* b4       = (const float*)d_in[10];
    const float* w_ih     = (const float*)d_in[11];
    const float* b_ih     = (const float*)d_in[12];
    const float* w_hh     = (const float*)d_in[13];
    const float* b_hh     = (const float*)d_in[14];
    const float* w_critic = (const float*)d_in[15];
    const float* b_critic = (const float*)d_in[16];
    const float* w_actor  = (const float*)d_in[17];
    const float* b_actor  = (const float*)d_in[18];
    const float* w_actor2 = (const float*)d_in[19];
    const float* b_actor2 = (const float*)d_in[20];
    float* out = (float*)d_out;
    unsigned long long* wsp = (unsigned long long*)d_ws;

    a3c_fwd<<<NB, TPB, 0, stream>>>(x, hx, cx, w1, b1, w2, b2, w3, b3, w4, b4,
                                    w_ih, b_ih, w_hh, b_hh,
                                    w_critic, b_critic, w_actor, b_actor,
                                    w_actor2, b_actor2, out, wsp);
}

// Round 12
// 103.317 us; speedup vs baseline: 1.0114x; 1.0114x over previous
//
#include <hip/hip_runtime.h>
#include <math.h>

// A3C batch-1 forward, R11: R9 structure + cooperative h1 inside team B.
//
// R9 (best, 100.7us bench): B16 blocks h1-redundant+16 h2 rows (46KB/blk),
// C4 h3, D4 h4, G8 gates+LSTM+heads, reducer folded into G0. R10 regressed
// (+3.8us): bigger B loads at the chain head + 8-producer H4 all-to-all.
// R11: keep R9's teams; B blocks now split w1 16 ways (1.9KB slice each),
// exchange h1 intra-team (H1 hop between hot blocks ~1us), cutting B's
// per-block load 46->18KB => first stage ready ~1.7us earlier.
//
// Teams (TPB=256, NB=32), hops H1(intra-B) -> H2 -> H3 -> H4 -> PT:
//   B: blk 0..15  16 h1 rows (w1 slice) -> exchange H1 -> 16 h2 rows
//                 (w2 16KB) -> send H2
//   C: blk 16..19 32 h3 rows (w3 32KB); recv H2 -> send H3
//   D: blk 20..23 32 h4 rows (w4 16KB); recv H3 -> send H4
//   G: blk 24..31 16 LSTM cells = 64 gate rows (w_hh+w_ih 64KB);
//                 g0=W_hh@hx early; recv H4 -> gates -> LSTM(16) ->
//                 7 head partials; G0 reduces 8x7, softsign, out.

#define NB   32
#define TPB  256
#define MAGIC 0x3A3C5A17u

#define H1_OFF 0      // 256 pairs (16 lines)
#define H2_OFF 256    // 256 pairs (16 lines)
#define H3_OFF 512    // 128 pairs (8 lines)
#define H4_OFF 640    // 128 pairs (8 lines)
#define PT_OFF 768    // 8 lines; G block g owns pairs [g*8 .. g*8+6]

__device__ __forceinline__ float lrelu(float v) { return v > 0.f ? v : 0.1f * v; }
__device__ __forceinline__ float sigm(float v)  { return 1.f / (1.f + __expf(-v)); }
__device__ __forceinline__ float dot4(float4 a, float4 b) {
    return a.x * b.x + a.y * b.y + a.z * b.z + a.w * b.w;
}

__device__ __forceinline__ void send(unsigned long long* p, float v) {
    unsigned lo = __float_as_uint(v);
    unsigned long long pk = (unsigned long long)lo |
                            ((unsigned long long)(lo ^ MAGIC) << 32);
    __hip_atomic_store(p, pk, __ATOMIC_RELAXED, __HIP_MEMORY_SCOPE_AGENT);
}
__device__ __forceinline__ float recv(unsigned long long* p) {
    unsigned long long pk =
        __hip_atomic_load(p, __ATOMIC_RELAXED, __HIP_MEMORY_SCOPE_AGENT);
    unsigned lo = (unsigned)pk, hi = (unsigned)(pk >> 32);
    if ((lo ^ MAGIC) == hi) return __uint_as_float(lo);
    __builtin_amdgcn_s_sleep(2);
    for (;;) {
        pk = __hip_atomic_load(p, __ATOMIC_RELAXED, __HIP_MEMORY_SCOPE_AGENT);
        lo = (unsigned)pk; hi = (unsigned)(pk >> 32);
        if ((lo ^ MAGIC) == hi) return __uint_as_float(lo);
        __builtin_amdgcn_s_sleep(8);
    }
}
__device__ __forceinline__ void touch(unsigned long long* p) {
    unsigned long long v =
        __hip_atomic_load(p, __ATOMIC_RELAXED, __HIP_MEMORY_SCOPE_AGENT);
    asm volatile("" :: "v"(v));
}

__global__ __launch_bounds__(TPB, 1) void a3c_fwd(
    const float* __restrict__ x, const float* __restrict__ hx, const float* __restrict__ cx,
    const float* __restrict__ w1, const float* __restrict__ b1,
    const float* __restrict__ w2, const float* __restrict__ b2,
    const float* __restrict__ w3, const float* __restrict__ b3,
    const float* __restrict__ w4, const float* __restrict__ b4,
    const float* __restrict__ w_ih, const float* __restrict__ b_ih,
    const float* __restrict__ w_hh, const float* __restrict__ b_hh,
    const float* __restrict__ w_critic, const float* __restrict__ b_critic,
    const float* __restrict__ w_actor, const float* __restrict__ b_actor,
    const float* __restrict__ w_actor2, const float* __restrict__ b_actor2,
    float* __restrict__ out, unsigned long long* __restrict__ wsp)
{
    const int blk = blockIdx.x, tid = threadIdx.x;

    if (blk < 16) {
        // ---- Team B: 16 h1 rows (w1 slice) + H1 exchange + 16 h2 rows ----
        const int b = blk;
        // prewarm: H1 recv set (16 lines) + own H2 send lines (2 lines)
        if (tid < 16)      touch(wsp + H1_OFF + tid * 16);
        else if (tid < 18) touch(wsp + H2_OFF + b * 16 + (tid - 16) * 8);

        // w1 slice: rows b*16.., 16 lanes/row, 2 floats/lane (cols p*2, p*2+1)
        const int r1 = b * 16 + (tid >> 4), p1 = tid & 15;
        const int c0 = p1 * 2;
        float a1x = 0.f, a1y = 0.f;
        if (c0 < 29)     a1x = w1[r1 * 29 + c0];
        if (c0 + 1 < 29) a1y = w1[r1 * 29 + c0 + 1];
        const float bb1 = b1[r1];

        // w2 slice: row r2 = b*16 + (tid>>4), 16 floats/lane
        const int r2 = r1, p2 = p1;
        float4 a2[4];
        {
            const float4* wp = (const float4*)(w2 + r2 * 256 + p2 * 16);
            #pragma unroll
            for (int j = 0; j < 4; ++j) a2[j] = wp[j];
        }
        const float bb2 = b2[r2];

        __shared__ __align__(16) float x_s[32];
        __shared__ __align__(16) float h1_s[256];
        if (tid < 32) x_s[tid] = (tid < 29) ? x[tid] : 0.f;
        __syncthreads();

        { // own 16 h1 rows -> LDS + send (a1x/a1y are 0 for OOB cols; x_s[30/31]=0)
            float s = a1x * x_s[c0] + a1y * x_s[c0 + 1];
            s += __shfl_xor(s, 1); s += __shfl_xor(s, 2);
            s += __shfl_xor(s, 4); s += __shfl_xor(s, 8);
            if (p1 == 0) {
                float v = lrelu(s + bb1);
                h1_s[r1] = v;
                send(wsp + H1_OFF + r1, v);
            }
        }
        // recv the other 240 h1 elements from the team
        if ((tid >> 4) != b) h1_s[tid] = recv(wsp + H1_OFF + tid);
        __syncthreads();

        { // 16 h2 rows
            const float4* hp = (const float4*)(h1_s + p2 * 16);
            float s = 0.f;
            #pragma unroll
            for (int j = 0; j < 4; ++j) s += dot4(a2[j], hp[j]);
            s += __shfl_xor(s, 1); s += __shfl_xor(s, 2);
            s += __shfl_xor(s, 4); s += __shfl_xor(s, 8);
            if (p2 == 0) send(wsp + H2_OFF + r2, lrelu(s + bb2));
        }
        return;
    }

    if (blk < 20) {
        // ---- Team C: 32 h3 rows/blk ----
        const int c = blk - 16;
        if (tid < 16)       touch(wsp + H2_OFF + tid * 16);                // recv set
        else if (tid < 20)  touch(wsp + H3_OFF + c * 32 + (tid - 16) * 8); // send

        const int r3 = c * 32 + (tid >> 3), p3 = tid & 7;
        float4 a3[8];
        {
            const float4* wp = (const float4*)(w3 + r3 * 256 + p3 * 32);
            #pragma unroll
            for (int j = 0; j < 8; ++j) a3[j] = wp[j];
        }
        const float bb3 = b3[r3];

        __shared__ __align__(16) float h2_s[256];
        h2_s[tid] = recv(wsp + H2_OFF + tid);
        __syncthreads();

        const float4* hp = (const float4*)(h2_s + p3 * 32);
        float s = 0.f;
        #pragma unroll
        for (int j = 0; j < 8; ++j) s += dot4(a3[j], hp[j]);
        s += __shfl_xor(s, 1); s += __shfl_xor(s, 2); s += __shfl_xor(s, 4);
        if (p3 == 0) send(wsp + H3_OFF + r3, lrelu(s + bb3));
        return;
    }

    if (blk < 24) {
        // ---- Team D: 32 h4 rows/blk ----
        const int d = blk - 20;
        if (tid < 8)        touch(wsp + H3_OFF + tid * 16);
        else if (tid < 12)  touch(wsp + H4_OFF + d * 32 + (tid - 8) * 8);

        const int r4 = d * 32 + (tid >> 3), p4 = tid & 7;
        float4 a4[4];
        {
            const float4* wp = (const float4*)(w4 + r4 * 128 + p4 * 16);
            #pragma unroll
            for (int j = 0; j < 4; ++j) a4[j] = wp[j];
        }
        const float bb4 = b4[r4];

        __shared__ __align__(16) float h3_s[128];
        if (tid < 128) h3_s[tid] = recv(wsp + H3_OFF + tid);
        __syncthreads();

        const float4* hp = (const float4*)(h3_s + p4 * 16);
        float s = 0.f;
        #pragma unroll
        for (int j = 0; j < 4; ++j) s += dot4(a4[j], hp[j]);
        s += __shfl_xor(s, 1); s += __shfl_xor(s, 2); s += __shfl_xor(s, 4);
        if (p4 == 0) send(wsp + H4_OFF + r4, lrelu(s + bb4));
        return;
    }

    // ---- Team G: 16 LSTM cells/blk (64 gate rows) + epilogue on G0 ----
    {
        const int g = blk - 24;                       // [0,8)
        if (tid < 8) touch(wsp + H4_OFF + tid * 16);  // recv set
        if (g > 0) { if (tid == 8) touch(wsp + PT_OFF + g * 8); }
        else       { if (tid >= 9 && tid < 16) touch(wsp + PT_OFF + (tid - 8) * 8); }

        const int r = tid >> 2, p = tid & 3;          // 64 rows x 4 lanes x 32
        const int gate = r >> 4, cell = r & 15;
        const int grow = gate * 128 + g * 16 + cell;

        float4 ah[8];
        {
            const float4* wp = (const float4*)(w_hh + grow * 128 + p * 32);
            #pragma unroll
            for (int j = 0; j < 8; ++j) ah[j] = wp[j];
        }
        float4 ai[8];
        {
            const float4* wp = (const float4*)(w_ih + grow * 128 + p * 32);
            #pragma unroll
            for (int j = 0; j < 8; ++j) ai[j] = wp[j];
        }
        const float bsum = b_ih[grow] + b_hh[grow];

        __shared__ __align__(16) float hx_s[128];
        __shared__ __align__(16) float h4_s[128];
        __shared__ __align__(16) float g_s[64];
        __shared__ __align__(16) float hn_s[16];
        __shared__ __align__(16) float hw_s[112];   // 7 heads x 16 cells
        __shared__ __align__(16) float hb_s[8];
        __shared__ __align__(16) float ps[64];      // G0: 7 heads x 8 blocks

        if (tid < 128) hx_s[tid] = hx[tid];
        float cxv = (tid < 16) ? cx[g * 16 + tid] : 0.f;
        if (tid < 112) {
            int o = tid >> 4, c = tid & 15;
            float v;
            if (o == 0)      v = w_critic[g * 16 + c];
            else if (o < 4)  v = w_actor [(o - 1) * 128 + g * 16 + c];
            else             v = w_actor2[(o - 4) * 128 + g * 16 + c];
            hw_s[tid] = v;
        }
        if (g == 0 && tid == 0) {
            hb_s[0] = b_critic[0];
            hb_s[1] = b_actor[0];  hb_s[2] = b_actor[1];  hb_s[3] = b_actor[2];
            hb_s[4] = b_actor2[0]; hb_s[5] = b_actor2[1]; hb_s[6] = b_actor2[2];
        }
        __syncthreads();

        // g0 = W_hh @ hx + biases (off critical path)
        float g0;
        {
            const float4* hp = (const float4*)(hx_s + p * 32);
            float s = 0.f;
            #pragma unroll
            for (int j = 0; j < 8; ++j) s += dot4(ah[j], hp[j]);
            s += __shfl_xor(s, 1); s += __shfl_xor(s, 2);
            g0 = s + bsum;
        }

        if (tid < 128) h4_s[tid] = recv(wsp + H4_OFF + tid);
        __syncthreads();

        { // gates for 64 rows
            const float4* hp = (const float4*)(h4_s + p * 32);
            float s = 0.f;
            #pragma unroll
            for (int j = 0; j < 8; ++j) s += dot4(ai[j], hp[j]);
            s += __shfl_xor(s, 1); s += __shfl_xor(s, 2);
            if (p == 0) g_s[r] = g0 + s;   // r = gate*16 + cell
        }
        __syncthreads();

        if (tid < 16) {   // LSTM elementwise, 16 cells
            float ig = g_s[tid];
            float fg = g_s[16 + tid];
            float gg = g_s[32 + tid];
            float og = g_s[48 + tid];
            float c  = sigm(fg) * cxv + sigm(ig) * tanhf(gg);
            hn_s[tid] = sigm(og) * tanhf(c);
        }
        __syncthreads();

        if (tid < 7) {    // 7 head partials over this block's 16 cells
            const float* wc = hw_s + tid * 16;
            float s = 0.f;
            #pragma unroll
            for (int j = 0; j < 16; ++j) s += wc[j] * hn_s[j];
            if (g > 0) send(wsp + PT_OFF + g * 8 + tid, s);
            else       ps[tid * 8] = s + hb_s[tid];
        }

        if (g == 0) {
            if (tid < 56) {
                const int gg = (tid >> 3) + 1, h = tid & 7;
                if (h < 7) ps[h * 8 + gg] = recv(wsp + PT_OFF + gg * 8 + h);
            }
            __syncthreads();
            if (tid < 7) {
                const float* row = ps + tid * 8;
                float s = row[0] + row[1] + row[2] + row[3]
                        + row[4] + row[5] + row[6] + row[7];
                if (tid >= 1 && tid <= 3) s = s / (1.f + fabsf(s));
                out[tid] = s;
            }
        }
    }
}

extern "C" void kernel_launch(void* const* d_in, const int* in_sizes, int n_in,
                              void* d_out, int out_size, void* d_ws, size_t ws_size,
                              hipStream_t stream) {
    const float* x        = (const float*)d_in[0];
    const float* hx       = (const float*)d_in[1];
    const float* cx       = (const float*)d_in[2];
    const float* w1       = (const float*)d_in[3];
    const float* b1       = (const float*)d_in[4];
    const float* w2       = (const float*)d_in[5];
    const float* b2       = (const float*)d_in[6];
    const float* w3       = (const float*)d_in[7];
    const float* b3       = (const float*)d_in[8];
    const float* w4       = (const float*)d_in[9];
    const float* b4       = (const float*)d_in[10];
    const float* w_ih     = (const float*)d_in[11];
    const float* b_ih     = (const float*)d_in[12];
    const float* w_hh     = (const float*)d_in[13];
    const float* b_hh     = (const float*)d_in[14];
    const float* w_critic = (const float*)d_in[15];
    const float* b_critic = (const float*)d_in[16];
    const float* w_actor  = (const float*)d_in[17];
    const float* b_actor  = (const float*)d_in[18];
    const float* w_actor2 = (const float*)d_in[19];
    const float* b_actor2 = (const float*)d_in[20];
    float* out = (float*)d_out;
    unsigned long long* wsp = (unsigned long long*)d_ws;

    a3c_fwd<<<NB, TPB, 0, stream>>>(x, hx, cx, w1, b1, w2, b2, w3, b3, w4, b4,
                                    w_ih, b_ih, w_hh, b_hh,
                                    w_critic, b_critic, w_actor, b_actor,
                                    w_actor2, b_actor2, out, wsp);
}

// Round 13
// 100.684 us; speedup vs baseline: 1.0378x; 1.0262x over previous
//
#include <hip/hip_runtime.h>
#include <math.h>

// A3C batch-1 forward, R12: R9 structure with teams C and D merged (CD).
//
// R9 = best (100.7us): B16 (h1 redundant + 16 h2 rows, 46KB) -> C4 (h3)
// -> D4 (h4) -> G8 (gates+LSTM+heads, reducer in G0). R10/R11 deviations
// (head-load growth, extra head hop, H4 all-to-all) all regressed.
// R12: merge C+D into CD4: each block 32 h3 rows (w3 32KB) -> send H3 ->
// recv other 96 (own 32 via LDS) -> 32 h4 rows (w4 16KB) -> send H4.
// Removes 4 cold-start blocks (NB 32->28) and makes the H3 hop an
// exchange among hot blocks. B and G unchanged from R9.
//
// Teams (TPB=256, NB=28), hops H2 -> H3(intra-CD) -> H4 -> PT:
//   B:  blk 0..15  h1 redundant (W1 30KB first) + 16 h2 rows -> send H2
//   CD: blk 16..19 recv H2 -> 32 h3 rows -> exchange H3 -> 32 h4 rows -> H4
//   G:  blk 20..27 16 LSTM cells = 64 gate rows (w_hh early for g0, w_ih);
//                  recv H4 -> gates -> LSTM(16) -> 7 head partials;
//                  G0 reduces 8x7, softsign, writes out.

#define NB   28
#define TPB  256
#define MAGIC 0x3A3C5A17u

#define H2_OFF 0      // 256 pairs (16 lines)
#define H3_OFF 256    // 128 pairs (8 lines)
#define H4_OFF 384    // 128 pairs (8 lines)
#define PT_OFF 512    // 8 lines; G block g owns pairs [g*8 .. g*8+6]

__device__ __forceinline__ float lrelu(float v) { return v > 0.f ? v : 0.1f * v; }
__device__ __forceinline__ float sigm(float v)  { return 1.f / (1.f + __expf(-v)); }
__device__ __forceinline__ float dot4(float4 a, float4 b) {
    return a.x * b.x + a.y * b.y + a.z * b.z + a.w * b.w;
}

__device__ __forceinline__ void send(unsigned long long* p, float v) {
    unsigned lo = __float_as_uint(v);
    unsigned long long pk = (unsigned long long)lo |
                            ((unsigned long long)(lo ^ MAGIC) << 32);
    __hip_atomic_store(p, pk, __ATOMIC_RELAXED, __HIP_MEMORY_SCOPE_AGENT);
}
__device__ __forceinline__ float recv(unsigned long long* p) {
    unsigned long long pk =
        __hip_atomic_load(p, __ATOMIC_RELAXED, __HIP_MEMORY_SCOPE_AGENT);
    unsigned lo = (unsigned)pk, hi = (unsigned)(pk >> 32);
    if ((lo ^ MAGIC) == hi) return __uint_as_float(lo);
    __builtin_amdgcn_s_sleep(2);
    for (;;) {
        pk = __hip_atomic_load(p, __ATOMIC_RELAXED, __HIP_MEMORY_SCOPE_AGENT);
        lo = (unsigned)pk; hi = (unsigned)(pk >> 32);
        if ((lo ^ MAGIC) == hi) return __uint_as_float(lo);
        __builtin_amdgcn_s_sleep(8);
    }
}
__device__ __forceinline__ void touch(unsigned long long* p) {
    unsigned long long v =
        __hip_atomic_load(p, __ATOMIC_RELAXED, __HIP_MEMORY_SCOPE_AGENT);
    asm volatile("" :: "v"(v));
}

__global__ __launch_bounds__(TPB, 1) void a3c_fwd(
    const float* __restrict__ x, const float* __restrict__ hx, const float* __restrict__ cx,
    const float* __restrict__ w1, const float* __restrict__ b1,
    const float* __restrict__ w2, const float* __restrict__ b2,
    const float* __restrict__ w3, const float* __restrict__ b3,
    const float* __restrict__ w4, const float* __restrict__ b4,
    const float* __restrict__ w_ih, const float* __restrict__ b_ih,
    const float* __restrict__ w_hh, const float* __restrict__ b_hh,
    const float* __restrict__ w_critic, const float* __restrict__ b_critic,
    const float* __restrict__ w_actor, const float* __restrict__ b_actor,
    const float* __restrict__ w_actor2, const float* __restrict__ b_actor2,
    float* __restrict__ out, unsigned long long* __restrict__ wsp)
{
    const int blk = blockIdx.x, tid = threadIdx.x;

    if (blk < 16) {
        // ---- Team B: h1 (redundant, W1 first) + 16 h2 rows (R9-identical) ----
        const int b = blk;
        if (tid == 0) touch(wsp + H2_OFF + b * 16);
        if (tid == 1) touch(wsp + H2_OFF + b * 16 + 8);

        float a1[29];
        {
            const float* w1r = w1 + tid * 29;
            #pragma unroll
            for (int j = 0; j < 29; ++j) a1[j] = w1r[j];
        }
        const float bb1 = b1[tid];

        const int r2 = b * 16 + (tid >> 4), p2 = tid & 15;
        float4 a2[4];
        {
            const float4* wp = (const float4*)(w2 + r2 * 256 + p2 * 16);
            #pragma unroll
            for (int j = 0; j < 4; ++j) a2[j] = wp[j];
        }
        const float bb2 = b2[r2];

        __shared__ __align__(16) float x_s[32];
        __shared__ __align__(16) float h1_s[256];
        if (tid < 32) x_s[tid] = (tid < 29) ? x[tid] : 0.f;
        __syncthreads();

        {
            float s = 0.f;
            #pragma unroll
            for (int j = 0; j < 29; ++j) s += a1[j] * x_s[j];
            h1_s[tid] = lrelu(s + bb1);
        }
        __syncthreads();

        {
            const float4* hp = (const float4*)(h1_s + p2 * 16);
            float s = 0.f;
            #pragma unroll
            for (int j = 0; j < 4; ++j) s += dot4(a2[j], hp[j]);
            s += __shfl_xor(s, 1); s += __shfl_xor(s, 2);
            s += __shfl_xor(s, 4); s += __shfl_xor(s, 8);
            if (p2 == 0) send(wsp + H2_OFF + r2, lrelu(s + bb2));
        }
        return;
    }

    if (blk < 20) {
        // ---- Team CD: 32 h3 rows -> exchange -> 32 h4 rows ----
        const int c = blk - 16;
        // prewarm: H2 recv (16 lines), H3 all (8 lines), own H4 send (4 lines)
        if (tid < 16)       touch(wsp + H2_OFF + tid * 16);
        else if (tid < 24)  touch(wsp + H3_OFF + (tid - 16) * 16);
        else if (tid < 28)  touch(wsp + H4_OFF + c * 32 + (tid - 24) * 8);

        // load order = need order: w3 first, then w4
        const int r3 = c * 32 + (tid >> 3), p3 = tid & 7;   // 32 floats/lane
        float4 a3[8];
        {
            const float4* wp = (const float4*)(w3 + r3 * 256 + p3 * 32);
            #pragma unroll
            for (int j = 0; j < 8; ++j) a3[j] = wp[j];
        }
        const float bb3 = b3[r3];

        const int r4 = c * 32 + (tid >> 3), p4 = tid & 7;   // 16 floats/lane
        float4 a4[4];
        {
            const float4* wp = (const float4*)(w4 + r4 * 128 + p4 * 16);
            #pragma unroll
            for (int j = 0; j < 4; ++j) a4[j] = wp[j];
        }
        const float bb4 = b4[r4];

        __shared__ __align__(16) float h2_s[256];
        __shared__ __align__(16) float h3_s[128];

        h2_s[tid] = recv(wsp + H2_OFF + tid);
        __syncthreads();

        { // own 32 h3 rows -> LDS + send
            const float4* hp = (const float4*)(h2_s + p3 * 32);
            float s = 0.f;
            #pragma unroll
            for (int j = 0; j < 8; ++j) s += dot4(a3[j], hp[j]);
            s += __shfl_xor(s, 1); s += __shfl_xor(s, 2); s += __shfl_xor(s, 4);
            if (p3 == 0) {
                float v = lrelu(s + bb3);
                h3_s[r3] = v;
                send(wsp + H3_OFF + r3, v);
            }
        }
        // recv the other 96 h3 elements from the team
        if (tid < 128 && (tid >> 5) != c) h3_s[tid] = recv(wsp + H3_OFF + tid);
        __syncthreads();

        { // own 32 h4 rows -> send
            const float4* hp = (const float4*)(h3_s + p4 * 16);
            float s = 0.f;
            #pragma unroll
            for (int j = 0; j < 4; ++j) s += dot4(a4[j], hp[j]);
            s += __shfl_xor(s, 1); s += __shfl_xor(s, 2); s += __shfl_xor(s, 4);
            if (p4 == 0) send(wsp + H4_OFF + r4, lrelu(s + bb4));
        }
        return;
    }

    // ---- Team G: 16 LSTM cells/blk (64 gate rows) + epilogue on G0 (R9) ----
    {
        const int g = blk - 20;                       // [0,8)
        if (tid < 8) touch(wsp + H4_OFF + tid * 16);  // recv set
        if (g > 0) { if (tid == 8) touch(wsp + PT_OFF + g * 8); }
        else       { if (tid >= 9 && tid < 16) touch(wsp + PT_OFF + (tid - 8) * 8); }

        const int r = tid >> 2, p = tid & 3;          // 64 rows x 4 lanes x 32
        const int gate = r >> 4, cell = r & 15;
        const int grow = gate * 128 + g * 16 + cell;

        float4 ah[8];
        {
            const float4* wp = (const float4*)(w_hh + grow * 128 + p * 32);
            #pragma unroll
            for (int j = 0; j < 8; ++j) ah[j] = wp[j];
        }
        float4 ai[8];
        {
            const float4* wp = (const float4*)(w_ih + grow * 128 + p * 32);
            #pragma unroll
            for (int j = 0; j < 8; ++j) ai[j] = wp[j];
        }
        const float bsum = b_ih[grow] + b_hh[grow];

        __shared__ __align__(16) float hx_s[128];
        __shared__ __align__(16) float h4_s[128];
        __shared__ __align__(16) float g_s[64];
        __shared__ __align__(16) float hn_s[16];
        __shared__ __align__(16) float hw_s[112];   // 7 heads x 16 cells
        __shared__ __align__(16) float hb_s[8];
        __shared__ __align__(16) float ps[64];      // G0: 7 heads x 8 blocks

        if (tid < 128) hx_s[tid] = hx[tid];
        float cxv = (tid < 16) ? cx[g * 16 + tid] : 0.f;
        if (tid < 112) {
            int o = tid >> 4, c = tid & 15;
            float v;
            if (o == 0)      v = w_critic[g * 16 + c];
            else if (o < 4)  v = w_actor [(o - 1) * 128 + g * 16 + c];
            else             v = w_actor2[(o - 4) * 128 + g * 16 + c];
            hw_s[tid] = v;
        }
        if (g == 0 && tid == 0) {
            hb_s[0] = b_critic[0];
            hb_s[1] = b_actor[0];  hb_s[2] = b_actor[1];  hb_s[3] = b_actor[2];
            hb_s[4] = b_actor2[0]; hb_s[5] = b_actor2[1]; hb_s[6] = b_actor2[2];
        }
        __syncthreads();

        // g0 = W_hh @ hx + biases (off critical path)
        float g0;
        {
            const float4* hp = (const float4*)(hx_s + p * 32);
            float s = 0.f;
            #pragma unroll
            for (int j = 0; j < 8; ++j) s += dot4(ah[j], hp[j]);
            s += __shfl_xor(s, 1); s += __shfl_xor(s, 2);
            g0 = s + bsum;
        }

        if (tid < 128) h4_s[tid] = recv(wsp + H4_OFF + tid);
        __syncthreads();

        { // gates for 64 rows
            const float4* hp = (const float4*)(h4_s + p * 32);
            float s = 0.f;
            #pragma unroll
            for (int j = 0; j < 8; ++j) s += dot4(ai[j], hp[j]);
            s += __shfl_xor(s, 1); s += __shfl_xor(s, 2);
            if (p == 0) g_s[r] = g0 + s;   // r = gate*16 + cell
        }
        __syncthreads();

        if (tid < 16) {   // LSTM elementwise, 16 cells
            float ig = g_s[tid];
            float fg = g_s[16 + tid];
            float gg = g_s[32 + tid];
            float og = g_s[48 + tid];
            float c  = sigm(fg) * cxv + sigm(ig) * tanhf(gg);
            hn_s[tid] = sigm(og) * tanhf(c);
        }
        __syncthreads();

        if (tid < 7) {    // 7 head partials over this block's 16 cells
            const float* wc = hw_s + tid * 16;
            float s = 0.f;
            #pragma unroll
            for (int j = 0; j < 16; ++j) s += wc[j] * hn_s[j];
            if (g > 0) send(wsp + PT_OFF + g * 8 + tid, s);
            else       ps[tid * 8] = s + hb_s[tid];
        }

        if (g == 0) {
            if (tid < 56) {
                const int gg = (tid >> 3) + 1, h = tid & 7;
                if (h < 7) ps[h * 8 + gg] = recv(wsp + PT_OFF + gg * 8 + h);
            }
            __syncthreads();
            if (tid < 7) {
                const float* row = ps + tid * 8;
                float s = row[0] + row[1] + row[2] + row[3]
                        + row[4] + row[5] + row[6] + row[7];
                if (tid >= 1 && tid <= 3) s = s / (1.f + fabsf(s));
                out[tid] = s;
            }
        }
    }
}

extern "C" void kernel_launch(void* const* d_in, const int* in_sizes, int n_in,
                              void* d_out, int out_size, void* d_ws, size_t ws_size,
                              hipStream_t stream) {
    const float* x        = (const float*)d_in[0];
    const float* hx       = (const float*)d_in[1];
    const float* cx       = (const float*)d_in[2];
    const float* w1       = (const float*)d_in[3];
    const float* b1       = (const float*)d_in[4];
    const float* w2       = (const float*)d_in[5];
    const float* b2       = (const float*)d_in[6];
    const float* w3       = (const float*)d_in[7];
    const float* b3       = (const float*)d_in[8];
    const float* w4       = (const float*)d_in[9];
    const float* b4       = (const float*)d_in[10];
    const float* w_ih     = (const float*)d_in[11];
    const float* b_ih     = (const float*)d_in[12];
    const float* w_hh     = (const float*)d_in[13];
    const float* b_hh     = (const float*)d_in[14];
    const float* w_critic = (const float*)d_in[15];
    const float* b_critic = (const float*)d_in[16];
    const float* w_actor  = (const float*)d_in[17];
    const float* b_actor  = (const float*)d_in[18];
    const float* w_actor2 = (const float*)d_in[19];
    const float* b_actor2 = (const float*)d_in[20];
    float* out = (float*)d_out;
    unsigned long long* wsp = (unsigned long long*)d_ws;

    a3c_fwd<<<NB, TPB, 0, stream>>>(x, hx, cx, w1, b1, w2, b2, w3, b3, w4, b4,
                                    w_ih, b_ih, w_hh, b_hh,
                                    w_critic, b_critic, w_actor, b_actor,
                                    w_actor2, b_actor2, out, wsp);
}